// Round 1
// baseline (216.529 us; speedup 1.0000x reference)
//
#include <hip/hip_runtime.h>

#define Bn 4096
#define Dn 66
#define Hn 512
#define BT 16

// Cmat[a*Hn + c] = W2[a,c] * M[c,a],  M[c,a] = sum_{i<Dn} W3[c,i] * W1[i,a]
__global__ __launch_bounds__(256) void k_cmat(
    const float* __restrict__ W1, const float* __restrict__ W2,
    const float* __restrict__ W3, float* __restrict__ Cmat)
{
    const int a = blockIdx.x;            // 0..511, uniform per block -> W1 col scalarizes
    for (int c = threadIdx.x; c < Hn; c += 256) {
        float m = 0.f;
        #pragma unroll
        for (int i = 0; i < Dn; ++i)
            m = fmaf(W3[c*Dn + i], W1[i*Hn + a], m);
        Cmat[a*Hn + c] = W2[a*Hn + c] * m;
    }
}

__global__ __launch_bounds__(256, 2) void k_main(
    const float* __restrict__ xs, const float* __restrict__ t,
    const float* __restrict__ W1, const float* __restrict__ b1,
    const float* __restrict__ W2, const float* __restrict__ b2,
    const float* __restrict__ W3, const float* __restrict__ b3,
    const float* __restrict__ Cmat, float* __restrict__ out)
{
    __shared__ float buf1[Hn*BT];   // h1 [a][r]  ->  h2 [c][r]
    __shared__ float buf2[Hn*BT];   // xT [i][r]  ->  s1 [a][r]  -> reduce scratch
    const int tid = threadIdx.x;
    const int r0  = blockIdx.x * BT;
    const int c0  = tid, c1 = tid + 256;

    // ---- stage x^T (row 66 = t) into buf2[i*BT + r] ----
    for (int idx = tid; idx < 67*BT; idx += 256) {
        const int i = idx >> 4, r = idx & (BT-1);
        buf2[i*BT + r] = (i < Dn) ? xs[(size_t)(r0+r)*Dn + i] : t[r0+r];
    }
    __syncthreads();

    // ---- Phase A: z1 for columns {c0,c1}, all BT rows ----
    float az0[BT], az1[BT];
    {
        const float bb0 = b1[c0], bb1 = b1[c1];
        #pragma unroll
        for (int r = 0; r < BT; ++r) { az0[r] = bb0; az1[r] = bb1; }
        for (int i = 0; i < 67; ++i) {
            const float w0 = W1[i*Hn + c0];
            const float w1 = W1[i*Hn + c1];
            const float4* xp = (const float4*)&buf2[i*BT];
            #pragma unroll
            for (int q = 0; q < 4; ++q) {
                const float4 x4 = xp[q];
                const float* xf = (const float*)&x4;
                #pragma unroll
                for (int rr = 0; rr < 4; ++rr) {
                    az0[q*4+rr] = fmaf(xf[rr], w0, az0[q*4+rr]);
                    az1[q*4+rr] = fmaf(xf[rr], w1, az1[q*4+rr]);
                }
            }
        }
    }
    __syncthreads();   // all xT reads finished; buf2 reusable

    // h1 -> buf1[a][r], s1' -> buf2[a][r]
    #pragma unroll
    for (int r = 0; r < BT; ++r) {
        float z = az0[r];
        float sg = 1.f / (1.f + __expf(-z));
        buf1[c0*BT + r] = z * sg;
        buf2[c0*BT + r] = sg * (1.f + z * (1.f - sg));
        z = az1[r];
        sg = 1.f / (1.f + __expf(-z));
        buf1[c1*BT + r] = z * sg;
        buf2[c1*BT + r] = sg * (1.f + z * (1.f - sg));
    }
    __syncthreads();

    // ---- Phase B: z2 = h1 @ W2  fused with  v = s1 @ Cmat ----
    float accz0[BT], accz1[BT], accv0[BT], accv1[BT];
    #pragma unroll
    for (int r = 0; r < BT; ++r) { accz0[r]=0.f; accz1[r]=0.f; accv0[r]=0.f; accv1[r]=0.f; }
    #pragma unroll 2
    for (int a = 0; a < Hn; ++a) {
        const float w0 = W2[a*Hn + c0], w1 = W2[a*Hn + c1];
        const float q0 = Cmat[a*Hn + c0], q1 = Cmat[a*Hn + c1];
        const float4* hp = (const float4*)&buf1[a*BT];
        const float4* sp = (const float4*)&buf2[a*BT];
        #pragma unroll
        for (int q = 0; q < 4; ++q) {
            const float4 h4 = hp[q];
            const float4 s4 = sp[q];
            const float* hf = (const float*)&h4;
            const float* sf = (const float*)&s4;
            #pragma unroll
            for (int rr = 0; rr < 4; ++rr) {
                accz0[q*4+rr] = fmaf(hf[rr], w0, accz0[q*4+rr]);
                accz1[q*4+rr] = fmaf(hf[rr], w1, accz1[q*4+rr]);
                accv0[q*4+rr] = fmaf(sf[rr], q0, accv0[q*4+rr]);
                accv1[q*4+rr] = fmaf(sf[rr], q1, accv1[q*4+rr]);
            }
        }
    }
    __syncthreads();   // buf1 (h1) / buf2 (s1) reads finished

    // ---- Epilogue: h2 -> buf1[c][r]; dp[r] = sum_c silu'(z2) * v ----
    float dp[BT];
    #pragma unroll
    for (int r = 0; r < BT; ++r) dp[r] = 0.f;
    {
        const float bb0 = b2[c0], bb1 = b2[c1];
        #pragma unroll
        for (int r = 0; r < BT; ++r) {
            float z = accz0[r] + bb0;
            float sg = 1.f / (1.f + __expf(-z));
            buf1[c0*BT + r] = z * sg;
            dp[r] = fmaf(sg * (1.f + z * (1.f - sg)), accv0[r], dp[r]);
            z = accz1[r] + bb1;
            sg = 1.f / (1.f + __expf(-z));
            buf1[c1*BT + r] = z * sg;
            dp[r] = fmaf(sg * (1.f + z * (1.f - sg)), accv1[r], dp[r]);
        }
    }
    // reduce dp over 256 threads (wave shuffle, then cross-wave via LDS)
    #pragma unroll
    for (int r = 0; r < BT; ++r) {
        float v = dp[r];
        v += __shfl_down(v, 32, 64);
        v += __shfl_down(v, 16, 64);
        v += __shfl_down(v,  8, 64);
        v += __shfl_down(v,  4, 64);
        v += __shfl_down(v,  2, 64);
        v += __shfl_down(v,  1, 64);
        if ((tid & 63) == 0) buf2[(tid >> 6)*BT + r] = v;
    }
    __syncthreads();
    if (tid < BT) {
        const float s = buf2[tid] + buf2[BT+tid] + buf2[2*BT+tid] + buf2[3*BT+tid];
        out[(size_t)Bn*Dn + r0 + tid] = -s;   // -div
    }

    // ---- Phase C: out = h2 @ W3 + b3 ----
    {
        const int jj = tid >> 2;     // j = 0..63
        const int rq = tid & 3;      // r block of 4
        float acc[4] = {0.f, 0.f, 0.f, 0.f};
        for (int c = 0; c < Hn; ++c) {
            const float w = W3[c*Dn + jj];
            const float4 h4 = *(const float4*)&buf1[c*BT + rq*4];
            const float* hf = (const float*)&h4;
            #pragma unroll
            for (int rr = 0; rr < 4; ++rr) acc[rr] = fmaf(hf[rr], w, acc[rr]);
        }
        const float bb = b3[jj];
        #pragma unroll
        for (int rr = 0; rr < 4; ++rr)
            out[(size_t)(r0 + rq*4 + rr)*Dn + jj] = acc[rr] + bb;
    }
    // leftover columns j = 64, 65
    if (tid < 2*BT) {
        const int j = Dn - 2 + (tid >> 4);
        const int r = tid & (BT-1);
        float acc = b3[j];
        for (int c = 0; c < Hn; ++c)
            acc = fmaf(buf1[c*BT + r], W3[c*Dn + j], acc);
        out[(size_t)(r0 + r)*Dn + j] = acc;
    }
}

extern "C" void kernel_launch(void* const* d_in, const int* in_sizes, int n_in,
                              void* d_out, int out_size, void* d_ws, size_t ws_size,
                              hipStream_t stream)
{
    const float* xs = (const float*)d_in[0];
    const float* t  = (const float*)d_in[1];
    const float* W1 = (const float*)d_in[2];
    const float* b1 = (const float*)d_in[3];
    const float* W2 = (const float*)d_in[4];
    const float* b2 = (const float*)d_in[5];
    const float* W3 = (const float*)d_in[6];
    const float* b3 = (const float*)d_in[7];
    float* out  = (float*)d_out;
    float* Cmat = (float*)d_ws;    // Hn*Hn floats = 1 MB

    k_cmat<<<Hn, 256, 0, stream>>>(W1, W2, W3, Cmat);
    k_main<<<Bn/BT, 256, 0, stream>>>(xs, t, W1, b1, W2, b2, W3, b3, Cmat, out);
}